// Round 6
// baseline (131.020 us; speedup 1.0000x reference)
//
#include <hip/hip_runtime.h>
#include <hip/hip_bf16.h>
#include <cstdint>
#include <cstddef>

#define B_ 8
#define C_ 256
#define N_ 2048
#define H_ 32
#define VP_ 2064            // vbf padded row stride (elems) = 4128 B
#define NT_ (N_ / 64)

typedef __bf16 bf8 __attribute__((ext_vector_type(8)));
typedef __bf16 bf4 __attribute__((ext_vector_type(4)));
typedef float f4 __attribute__((ext_vector_type(4)));

__device__ inline void gload_lds16(const void* g, void* l) {
  __builtin_amdgcn_global_load_lds(
      (const __attribute__((address_space(1))) unsigned int*)g,
      (__attribute__((address_space(3))) unsigned int*)l, 16, 0, 0);
}

// ---- P1: pack weights: wpk bf16 [320][256] = {wv; wq; wk}, bpk fp32 [320] ----
// wq/bq pre-scaled by log2(e): fused kernel uses raw v_exp_f32 (exp2).
__global__ __launch_bounds__(256) void pack_kernel(
    const float* __restrict__ wq, const float* __restrict__ wk,
    const float* __restrict__ wv, const float* __restrict__ bq,
    const float* __restrict__ bk, const float* __restrict__ bv,
    __hip_bfloat16* __restrict__ wpk, float* __restrict__ bpk) {
  const float L2E = 1.44269504088896f;
  int r = blockIdx.x, c = threadIdx.x;
  float v;
  if (r < 256)      v = wv[r * 256 + c];
  else if (r < 288) v = wq[(r - 256) * 256 + c] * L2E;
  else              v = wk[(r - 288) * 256 + c];
  wpk[r * 256 + c] = __float2bfloat16(v);
  if (c == 0) bpk[r] = (r < 256) ? bv[r] : (r < 288 ? bq[r - 256] * L2E : bk[r - 288]);
}

// ---- P2: proj GEMM. ONE CHANGE vs R5: vbf rows are stored with a j-permutation
// inside each 32-elem chunk: pos(x) = ((x>>2)&3)*8 + (x>>4)*4 + (x&3), so the
// fused kernel's PV B-fragment (k = lg*8+e <-> j = (e>>2)*16 + lg*4 + (e&3))
// is one contiguous 16B load per lane.
__global__ __launch_bounds__(256) void proj_kernel(
    const float* __restrict__ x, const __hip_bfloat16* __restrict__ wpk,
    const float* __restrict__ bpk, __hip_bfloat16* __restrict__ vbf,
    __hip_bfloat16* __restrict__ qkb) {
  __shared__ __attribute__((aligned(16))) __hip_bfloat16 As[2][320 * 32];  // 40 KB
  int tid = threadIdx.x, wv = tid >> 6, lane = tid & 63;
  int b = blockIdx.y;
  int n0 = blockIdx.x * 32;
  int fcol = lane & 15, hi4 = lane >> 4;
  int grow = lane >> 2, gc = (lane & 3) * 8;
  const float* xb = x + (size_t)b * C_ * N_;

#pragma unroll
  for (int g = 0; g < 5; ++g)
    gload_lds16(wpk + (size_t)(wv * 80 + g * 16 + grow) * 256 + gc,
                &As[0][(wv * 80 + g * 16) * 32]);
  float xr[2][8];
#pragma unroll
  for (int j = 0; j < 2; ++j)
#pragma unroll
    for (int e = 0; e < 8; ++e)
      xr[j][e] = xb[(size_t)(hi4 * 8 + e) * N_ + n0 + j * 16 + fcol];

  f4 acc[5][2] = {};
  for (int t = 0; t < 8; ++t) {
    int buf = t & 1;
    __syncthreads();
    if (t < 7) {
      int k1 = (t + 1) * 32;
#pragma unroll
      for (int g = 0; g < 5; ++g)
        gload_lds16(wpk + (size_t)(wv * 80 + g * 16 + grow) * 256 + k1 + gc,
                    &As[buf ^ 1][(wv * 80 + g * 16) * 32]);
    }
    bf8 bfr[2];
#pragma unroll
    for (int j = 0; j < 2; ++j)
#pragma unroll
      for (int e = 0; e < 8; ++e) bfr[j][e] = (__bf16)xr[j][e];
    if (t < 7) {
      int k1 = (t + 1) * 32;
#pragma unroll
      for (int j = 0; j < 2; ++j)
#pragma unroll
        for (int e = 0; e < 8; ++e)
          xr[j][e] = xb[(size_t)(k1 + hi4 * 8 + e) * N_ + n0 + j * 16 + fcol];
    }
#pragma unroll
    for (int s = 0; s < 5; ++s) {
      bf8 af = *(const bf8*)&As[buf][(wv * 80 + s * 16 + fcol) * 32 + hi4 * 8];
      acc[s][0] = __builtin_amdgcn_mfma_f32_16x16x32_bf16(af, bfr[0], acc[s][0], 0, 0, 0);
      acc[s][1] = __builtin_amdgcn_mfma_f32_16x16x32_bf16(af, bfr[1], acc[s][1], 0, 0, 0);
    }
  }
  int rq = hi4 * 4;
#pragma unroll
  for (int s = 0; s < 5; ++s)
#pragma unroll
    for (int r = 0; r < 4; ++r) {
      int m = wv * 80 + s * 16 + rq + r;
      float bias = bpk[m];
#pragma unroll
      for (int j = 0; j < 2; ++j) {
        int n = n0 + j * 16 + fcol;
        float val = acc[s][j][r] + bias;
        if (m < 256) {
          // permuted within 32-chunk: x = j*16+fcol -> (fcol>>2)*8 + j*4 + (fcol&3)
          int nsw = n0 + ((fcol >> 2) << 3) + (j << 2) + (fcol & 3);
          vbf[((size_t)b * C_ + m) * VP_ + nsw] = __float2bfloat16(val);
        } else {
          qkb[((size_t)b * N_ + n) * 64 + (m - 256)] = __float2bfloat16(val);
        }
      }
    }
}

// ---- fused attention v9: barrier-free main loop, P never leaves registers.
// Block c128 x i64 (grid 512, 4 waves). Wave (cw, jw): c-half cw (64 rows),
// ALL i (64), j-half jw. S is duplicated across cw (cheap: exp2 only); PV
// consumes the wave's OWN S output as the MFMA A-operand directly:
//   S^T lane (li,lg) holds P[i = is*16+li][j = js*16+lg*4+m]
//   -> pa8[is] elems e<4 = js0 m=e, e>=4 = js1 m=e-4: A[k=lg*8+e] with
//      j(k) = (e>>2)*16 + lg*4 + (e&3)
//   -> B = V with matching j(k), one 16B load thanks to proj's permuted vbf.
// acc comes out transposed (i=row, c=col); a one-time epilogue LDS pass does
// the transpose AND the cross-jw partial-sum combine. Zero LDS/barriers in
// the 32-iteration main loop.
#define ATTN_BODY(T, KS)                                                       \
  {                                                                            \
    f4 s0[4], s1[4];                                                           \
    _Pragma("unroll")                                                          \
    for (int is = 0; is < 4; ++is) {                                           \
      f4 z = {};                                                               \
      s0[is] = __builtin_amdgcn_mfma_f32_16x16x32_bf16(KS[0], qf[is], z, 0, 0, 0); \
      s1[is] = __builtin_amdgcn_mfma_f32_16x16x32_bf16(KS[1], qf[is], z, 0, 0, 0); \
    }                                                                          \
    {                                                                          \
      int tn_ = (T) + 2 < NT_ ? (T) + 2 : NT_ - 1;                             \
      KS[0] = *(const bf8*)(kp + (size_t)(tn_ * 64) * 64);                     \
      KS[1] = *(const bf8*)(kp + (size_t)(tn_ * 64 + 16) * 64);                \
    }                                                                          \
    bf8 pa[4];                                                                 \
    _Pragma("unroll")                                                          \
    for (int is = 0; is < 4; ++is) {                                           \
      _Pragma("unroll")                                                        \
      for (int m = 0; m < 4; ++m) {                                            \
        s0[is][m] = __builtin_amdgcn_exp2f(s0[is][m]);                         \
        s1[is][m] = __builtin_amdgcn_exp2f(s1[is][m]);                         \
      }                                                                        \
      lp[is] += s0[is][0] + s0[is][1] + s0[is][2] + s0[is][3]                  \
              + s1[is][0] + s1[is][1] + s1[is][2] + s1[is][3];                 \
      _Pragma("unroll")                                                        \
      for (int m = 0; m < 4; ++m) {                                            \
        pa[is][m]     = (__bf16)s0[is][m];                                     \
        pa[is][4 + m] = (__bf16)s1[is][m];                                     \
      }                                                                        \
    }                                                                          \
    __builtin_amdgcn_s_setprio(1);                                             \
    _Pragma("unroll")                                                          \
    for (int cs = 0; cs < 4; ++cs)                                             \
      _Pragma("unroll")                                                        \
      for (int is = 0; is < 4; ++is)                                           \
        acc[cs][is] = __builtin_amdgcn_mfma_f32_16x16x32_bf16(                 \
            pa[is], vb[cs], acc[cs][is], 0, 0, 0);                             \
    __builtin_amdgcn_s_setprio(0);                                             \
    {                                                                          \
      int tn_ = (T) + 1 < NT_ ? (T) + 1 : NT_ - 1;                             \
      _Pragma("unroll")                                                        \
      for (int cs = 0; cs < 4; ++cs)                                           \
        vb[cs] = *(const bf8*)(vBp + (size_t)cs * 16 * VP_ + tn_ * 64);        \
    }                                                                          \
  }

__global__ __launch_bounds__(256, 2) void fused_attn(
    const __hip_bfloat16* __restrict__ qk,   // [b][n][64]: q 0..31, k 32..63
    const __hip_bfloat16* __restrict__ vbf,  // [b][c][VP_], j-permuted chunks
    const float* __restrict__ x, float* __restrict__ out) {
  __shared__ __attribute__((aligned(16))) float aS[2][128][68];  // 69.6 KB
  __shared__ float lSp[2][64];
  __shared__ __attribute__((aligned(16))) float linvS[64];
  int tid = threadIdx.x;
  int wv = tid >> 6, lane = tid & 63;
  int li = lane & 15, lg = lane >> 4;
  int lg8 = lg * 8, lg4 = lg * 4;
  int cw = wv >> 1, jw = wv & 1;
  // XCD-pinning: b = blk&7 pins batch b's 64 blocks to one XCD's L2.
  int blk = blockIdx.x;
  int b = blk & 7;
  int rest = blk >> 3;
  int c0 = (rest & 1) * 128;
  int i0 = (rest >> 1) * 64;

  const __hip_bfloat16* qkB = qk + (size_t)b * N_ * 64;
  // Q B-frags: col i = i0 + is*16 + li, k = h = lg*8+e
  bf8 qf[4];
#pragma unroll
  for (int is = 0; is < 4; ++is)
    qf[is] = *(const bf8*)&qkB[(size_t)(i0 + is * 16 + li) * 64 + lg8];
  // K A-frag base: row j = t*64 + jw*32 + js*16 + li, k = h (offset 32)
  const __hip_bfloat16* kp = qkB + (size_t)(jw * 32 + li) * 64 + 32 + lg8;
  // V B-frag base: col c = c0 + cw*64 + cs*16 + li, k-chunk at permuted lg*8
  const __hip_bfloat16* vBp =
      vbf + ((size_t)b * C_ + c0 + cw * 64 + li) * VP_ + jw * 32 + lg8;

  bf8 kE[2], kO[2], vb[4];
#pragma unroll
  for (int js = 0; js < 2; ++js) {
    kE[js] = *(const bf8*)(kp + (size_t)(js * 16) * 64);
    kO[js] = *(const bf8*)(kp + (size_t)(64 + js * 16) * 64);
  }
#pragma unroll
  for (int cs = 0; cs < 4; ++cs)
    vb[cs] = *(const bf8*)(vBp + (size_t)cs * 16 * VP_);

  f4 acc[4][4] = {};
  float lp[4] = {0.f, 0.f, 0.f, 0.f};

  for (int tt = 0; tt < NT_; tt += 2) {
    ATTN_BODY(tt, kE)
    ATTN_BODY(tt + 1, kO)
  }
#undef ATTN_BODY

  // Epilogue 1: dump transposed acc to LDS (i-contiguous f4 rows) per jw.
#pragma unroll
  for (int cs = 0; cs < 4; ++cs)
#pragma unroll
    for (int is = 0; is < 4; ++is)
      *(f4*)&aS[jw][cw * 64 + cs * 16 + li][is * 16 + lg4] = acc[cs][is];

  // softmax denominator: per-lane partial (own lg's j-subset) -> lg reduce.
#pragma unroll
  for (int is = 0; is < 4; ++is) {
    lp[is] += __shfl_xor(lp[is], 16);
    lp[is] += __shfl_xor(lp[is], 32);
  }
  if (cw == 0 && lane < 16) {
#pragma unroll
    for (int is = 0; is < 4; ++is) lSp[jw][is * 16 + lane] = lp[is];
  }
  __syncthreads();
  if (tid < 64) linvS[tid] = 1.0f / (lSp[0][tid] + lSp[1][tid]);
  __syncthreads();

  // Epilogue 2: combine jw-partials, scale, add residual, coalesced f4 store.
  const float* xB = x + ((size_t)b * C_ + c0) * N_ + i0;
  float* oB = out + ((size_t)b * C_ + c0) * N_ + i0;
  int cr = tid >> 4, i4 = (tid & 15) * 4;
  f4 lv = *(const f4*)&linvS[i4];
#pragma unroll
  for (int q = 0; q < 8; ++q) {
    int c = q * 16 + cr;
    f4 a0 = *(const f4*)&aS[0][c][i4];
    f4 a1 = *(const f4*)&aS[1][c][i4];
    f4 xv = *(const f4*)(xB + (size_t)c * N_ + i4);
    f4 o;
#pragma unroll
    for (int e = 0; e < 4; ++e) o[e] = (a0[e] + a1[e]) * lv[e] + xv[e];
    *(f4*)(oB + (size_t)c * N_ + i4) = o;
  }
}

extern "C" void kernel_launch(void* const* d_in, const int* in_sizes, int n_in,
                              void* d_out, int out_size, void* d_ws, size_t ws_size,
                              hipStream_t stream) {
  const float* x  = (const float*)d_in[0];
  const float* wq = (const float*)d_in[1];
  const float* bq = (const float*)d_in[2];
  const float* wk = (const float*)d_in[3];
  const float* bk = (const float*)d_in[4];
  const float* wv = (const float*)d_in[5];
  const float* bv = (const float*)d_in[6];
  float* out = (float*)d_out;

  char* ws = (char*)d_ws;
  __hip_bfloat16* qkb = (__hip_bfloat16*)ws;                        // 2 MiB [b][n][64]
  __hip_bfloat16* vbf = (__hip_bfloat16*)(ws + (2u << 20));         // 8.06 MiB [b][c][VP_]
  __hip_bfloat16* wpk = (__hip_bfloat16*)(ws + 10551296u);          // 160 KiB [320][256]
  float*          bpk = (float*)(ws + 10551296u + 163840u);

  pack_kernel<<<dim3(320), 256, 0, stream>>>(wq, wk, wv, bq, bk, bv, wpk, bpk);
  proj_kernel<<<dim3(N_ / 32, B_), 256, 0, stream>>>(x, wpk, bpk, vbf, qkb);
  fused_attn<<<dim3(512), 256, 0, stream>>>(qkb, vbf, x, out);
}

// Round 7
// 127.493 us; speedup vs baseline: 1.0277x; 1.0277x over previous
//
#include <hip/hip_runtime.h>
#include <hip/hip_bf16.h>
#include <cstdint>
#include <cstddef>

#define B_ 8
#define C_ 256
#define N_ 2048
#define H_ 32
#define VP_ 2064            // vbf padded row stride (elems) = 4128 B
#define NT_ (N_ / 64)

typedef __bf16 bf8 __attribute__((ext_vector_type(8)));
typedef __bf16 bf4 __attribute__((ext_vector_type(4)));
typedef float f4 __attribute__((ext_vector_type(4)));

__device__ inline void gload_lds16(const void* g, void* l) {
  __builtin_amdgcn_global_load_lds(
      (const __attribute__((address_space(1))) unsigned int*)g,
      (__attribute__((address_space(3))) unsigned int*)l, 16, 0, 0);
}

// ---- P1: pack weights: wpk bf16 [320][256] = {wv; wq; wk}, bpk fp32 [320] ----
// wq/bq pre-scaled by log2(e): fused kernel uses raw v_exp_f32 (exp2).
__global__ __launch_bounds__(256) void pack_kernel(
    const float* __restrict__ wq, const float* __restrict__ wk,
    const float* __restrict__ wv, const float* __restrict__ bq,
    const float* __restrict__ bk, const float* __restrict__ bv,
    __hip_bfloat16* __restrict__ wpk, float* __restrict__ bpk) {
  const float L2E = 1.44269504088896f;
  int r = blockIdx.x, c = threadIdx.x;
  float v;
  if (r < 256)      v = wv[r * 256 + c];
  else if (r < 288) v = wq[(r - 256) * 256 + c] * L2E;
  else              v = wk[(r - 288) * 256 + c];
  wpk[r * 256 + c] = __float2bfloat16(v);
  if (c == 0) bpk[r] = (r < 256) ? bv[r] : (r < 288 ? bq[r - 256] * L2E : bk[r - 288]);
}

// ---- P2: proj GEMM v3: x staged through LDS via global_load_lds (coalesced,
// 2-body prefetch depth, triple-buffered) + counted-vmcnt raw barrier.
// Per body t: vmcnt(1)+s_barrier (forces wpk(t)+x(t) landed; newest x load
// stays in flight) -> issue wpk(t+1) x5 -> issue x(t+2) LAST -> B-frags from
// xS[t%3] ds_reads -> 10 MFMA. x-load latency window = 2 bodies (~1200 cyc
// > ~900 cyc HBM miss), vs 1 body + full vmcnt(0) drain before.
__global__ __launch_bounds__(256) void proj_kernel(
    const float* __restrict__ x, const __hip_bfloat16* __restrict__ wpk,
    const float* __restrict__ bpk, __hip_bfloat16* __restrict__ vbf,
    __hip_bfloat16* __restrict__ qkb) {
  __shared__ __attribute__((aligned(16))) __hip_bfloat16 As[2][320 * 32];  // 40 KB
  __shared__ __attribute__((aligned(16))) float xS[3][32 * 32];            // 12 KB
  int tid = threadIdx.x, wv = tid >> 6, lane = tid & 63;
  int b = blockIdx.y;
  int n0 = blockIdx.x * 32;
  int fcol = lane & 15, hi4 = lane >> 4;
  int grow = lane >> 2, gc = (lane & 3) * 8;               // wpk staging
  int xrow = wv * 8 + (lane >> 3), xcq = (lane & 7) * 4;   // x staging
  const float* xb = x + (size_t)b * C_ * N_;

  // prologue: wpk(0) x5, x(0), x(1) — x(1) issued last so vmcnt(1) at loop
  // top completes wpk(0)+x(0) and leaves x(1) in flight.
#pragma unroll
  for (int g = 0; g < 5; ++g)
    gload_lds16(wpk + (size_t)(wv * 80 + g * 16 + grow) * 256 + gc,
                &As[0][(wv * 80 + g * 16) * 32]);
  gload_lds16(xb + (size_t)xrow * N_ + n0 + xcq, &xS[0][wv * 8 * 32]);
  gload_lds16(xb + (size_t)(32 + xrow) * N_ + n0 + xcq, &xS[1][wv * 8 * 32]);

  f4 acc[5][2] = {};
  for (int t = 0; t < 8; ++t) {
    int buf = t & 1;
    if (t < 7)
      asm volatile("s_waitcnt vmcnt(1)" ::: "memory");
    else
      asm volatile("s_waitcnt vmcnt(0)" ::: "memory");
    __builtin_amdgcn_s_barrier();
    __builtin_amdgcn_sched_barrier(0);
    if (t < 7) {
      int k1 = (t + 1) * 32;
#pragma unroll
      for (int g = 0; g < 5; ++g)
        gload_lds16(wpk + (size_t)(wv * 80 + g * 16 + grow) * 256 + k1 + gc,
                    &As[buf ^ 1][(wv * 80 + g * 16) * 32]);
    }
    if (t < 6) {
      int k2 = (t + 2) * 32;
      gload_lds16(xb + (size_t)(k2 + xrow) * N_ + n0 + xcq,
                  &xS[(t + 2) % 3][wv * 8 * 32]);
    }
    const float* xt = &xS[t % 3][0];
    bf8 bfr[2];
#pragma unroll
    for (int j = 0; j < 2; ++j)
#pragma unroll
      for (int e = 0; e < 8; ++e)
        bfr[j][e] = (__bf16)xt[(hi4 * 8 + e) * 32 + j * 16 + fcol];
#pragma unroll
    for (int s = 0; s < 5; ++s) {
      bf8 af = *(const bf8*)&As[buf][(wv * 80 + s * 16 + fcol) * 32 + hi4 * 8];
      acc[s][0] = __builtin_amdgcn_mfma_f32_16x16x32_bf16(af, bfr[0], acc[s][0], 0, 0, 0);
      acc[s][1] = __builtin_amdgcn_mfma_f32_16x16x32_bf16(af, bfr[1], acc[s][1], 0, 0, 0);
    }
  }
  int rq = hi4 * 4;
#pragma unroll
  for (int s = 0; s < 5; ++s)
#pragma unroll
    for (int r = 0; r < 4; ++r) {
      int m = wv * 80 + s * 16 + rq + r;
      float bias = bpk[m];
#pragma unroll
      for (int j = 0; j < 2; ++j) {
        int n = n0 + j * 16 + fcol;
        float val = acc[s][j][r] + bias;
        if (m < 256)
          vbf[((size_t)b * C_ + m) * VP_ + n] = __float2bfloat16(val);
        else
          qkb[((size_t)b * N_ + n) * 64 + (m - 256)] = __float2bfloat16(val);
      }
    }
}

// ---- fused attention v8 (R5, best measured ~43 µs): 16x16x32 fragments,
// LDS P-exchange, cross-barrier software pipeline, lgkm-only barrier drain.
#define MFMA16(A, B, C) __builtin_amdgcn_mfma_f32_16x16x32_bf16(A, B, C, 0, 0, 0)

#define ATTN_BODY(T, BUF, KC0, KC1, KN0, KN1, VA, VB, VC, VD)                  \
  {                                                                            \
    bf8 pf00 = *(const bf8*)&pS[BUF][ 0 + li][ 0 + lg8];                       \
    bf8 pf10 = *(const bf8*)&pS[BUF][16 + li][ 0 + lg8];                       \
    bf8 pf20 = *(const bf8*)&pS[BUF][32 + li][ 0 + lg8];                       \
    bf8 pf30 = *(const bf8*)&pS[BUF][48 + li][ 0 + lg8];                       \
    bf8 pf01 = *(const bf8*)&pS[BUF][ 0 + li][32 + lg8];                       \
    bf8 pf11 = *(const bf8*)&pS[BUF][16 + li][32 + lg8];                       \
    bf8 pf21 = *(const bf8*)&pS[BUF][32 + li][32 + lg8];                       \
    bf8 pf31 = *(const bf8*)&pS[BUF][48 + li][32 + lg8];                       \
    f4 s00 = {}, s01 = {}, s10 = {}, s11 = {};                                 \
    if ((T) + 1 < NT_) {                                                       \
      s00 = MFMA16(KC0, qf0, s00);                                             \
      s01 = MFMA16(KC0, qf1, s01);                                             \
      s10 = MFMA16(KC1, qf0, s10);                                             \
      s11 = MFMA16(KC1, qf1, s11);                                             \
    }                                                                          \
    {                                                                          \
      int tn_ = (T) + 2 < NT_ ? (T) + 2 : NT_ - 1;                             \
      const __hip_bfloat16* kpn_ = kp + (size_t)tn_ * 64 * 64;                 \
      KN0 = *(const bf8*)kpn_;                                                 \
      KN1 = *(const bf8*)(kpn_ + 16 * 64);                                     \
    }                                                                          \
    __builtin_amdgcn_s_setprio(1);                                             \
    acc[0][0] = MFMA16(VA, pf00, acc[0][0]);                                   \
    acc[0][1] = MFMA16(VA, pf10, acc[0][1]);                                   \
    acc[0][2] = MFMA16(VA, pf20, acc[0][2]);                                   \
    acc[0][3] = MFMA16(VA, pf30, acc[0][3]);                                   \
    acc[1][0] = MFMA16(VC, pf00, acc[1][0]);                                   \
    acc[1][1] = MFMA16(VC, pf10, acc[1][1]);                                   \
    acc[1][2] = MFMA16(VC, pf20, acc[1][2]);                                   \
    acc[1][3] = MFMA16(VC, pf30, acc[1][3]);                                   \
    acc[0][0] = MFMA16(VB, pf01, acc[0][0]);                                   \
    acc[0][1] = MFMA16(VB, pf11, acc[0][1]);                                   \
    acc[0][2] = MFMA16(VB, pf21, acc[0][2]);                                   \
    acc[0][3] = MFMA16(VB, pf31, acc[0][3]);                                   \
    acc[1][0] = MFMA16(VD, pf01, acc[1][0]);                                   \
    acc[1][1] = MFMA16(VD, pf11, acc[1][1]);                                   \
    acc[1][2] = MFMA16(VD, pf21, acc[1][2]);                                   \
    acc[1][3] = MFMA16(VD, pf31, acc[1][3]);                                   \
    __builtin_amdgcn_s_setprio(0);                                             \
    {                                                                          \
      int tn_ = (T) + 2 < NT_ ? (T) + 2 : NT_ - 1;                             \
      const __hip_bfloat16* vpn_ = vR + tn_ * 64;                              \
      VA = *(const bf8*)vpn_;                                                  \
      VB = *(const bf8*)(vpn_ + 32);                                           \
      VC = *(const bf8*)(vpn_ + 16 * VP_);                                     \
      VD = *(const bf8*)(vpn_ + 16 * VP_ + 32);                                \
    }                                                                          \
    if ((T) + 1 < NT_) {                                                       \
      _Pragma("unroll")                                                        \
      for (int m = 0; m < 4; ++m) {                                            \
        s00[m] = __builtin_amdgcn_exp2f(s00[m]);                               \
        s01[m] = __builtin_amdgcn_exp2f(s01[m]);                               \
        s10[m] = __builtin_amdgcn_exp2f(s10[m]);                               \
        s11[m] = __builtin_amdgcn_exp2f(s11[m]);                               \
      }                                                                        \
      _Pragma("unroll")                                                        \
      for (int m = 0; m < 4; ++m) {                                            \
        lp0 += s00[m] + s10[m];                                                \
        lp1 += s01[m] + s11[m];                                                \
      }                                                                        \
      {                                                                        \
        bf4 t0, t1, t2, t3;                                                    \
        _Pragma("unroll")                                                      \
        for (int m = 0; m < 4; ++m) {                                          \
          t0[m] = (__bf16)s00[m]; t1[m] = (__bf16)s01[m];                      \
          t2[m] = (__bf16)s10[m]; t3[m] = (__bf16)s11[m];                      \
        }                                                                      \
        *(bf4*)&pS[(BUF) ^ 1][ws_i * 32 +  0 + li][ws_j * 32 +  0 + lg4] = t0; \
        *(bf4*)&pS[(BUF) ^ 1][ws_i * 32 + 16 + li][ws_j * 32 +  0 + lg4] = t1; \
        *(bf4*)&pS[(BUF) ^ 1][ws_i * 32 +  0 + li][ws_j * 32 + 16 + lg4] = t2; \
        *(bf4*)&pS[(BUF) ^ 1][ws_i * 32 + 16 + li][ws_j * 32 + 16 + lg4] = t3; \
      }                                                                        \
      asm volatile("s_waitcnt lgkmcnt(0)" ::: "memory");                       \
      __builtin_amdgcn_sched_barrier(0);                                       \
      __builtin_amdgcn_s_barrier();                                            \
      __builtin_amdgcn_sched_barrier(0);                                       \
    }                                                                          \
  }

__global__ __launch_bounds__(256, 2) void fused_attn(
    const __hip_bfloat16* __restrict__ qk,   // [b][n][64]: q 0..31, k 32..63
    const __hip_bfloat16* __restrict__ vbf,  // [b][c][VP_]
    const float* __restrict__ x, float* __restrict__ out) {
  __shared__ __attribute__((aligned(16))) __hip_bfloat16 pS[2][64][88];  // 22 KB
  __shared__ float lSp[2][64];
  int tid = threadIdx.x;
  int wv = tid >> 6, lane = tid & 63;
  int li = lane & 15, lg = lane >> 4;       // 16x16 frag coords
  int lg8 = lg * 8, lg4 = lg * 4;
  int ws_i = wv >> 1, ws_j = wv & 1;
  // XCD-pinning: b = blk&7 pins batch b's 64 blocks to one XCD's L2.
  int blk = blockIdx.x;
  int b = blk & 7;
  int rest = blk >> 3;
  int c0 = (rest & 1) * 128;
  int i0 = (rest >> 1) * 64;

  const __hip_bfloat16* qkB = qk + (size_t)b * N_ * 64;
  // Q B-frags (16x16x32): col i = i0+ws_i*32+isub*16+li, k = h = lg*8+e
  bf8 qf0 = *(const bf8*)&qkB[(size_t)(i0 + ws_i * 32 +  0 + li) * 64 + lg8];
  bf8 qf1 = *(const bf8*)&qkB[(size_t)(i0 + ws_i * 32 + 16 + li) * 64 + lg8];
  // K A-frag base: row j = t*64 + ws_j*32 + jsub*16 + li, k = h (offset 32)
  const __hip_bfloat16* kp = qkB + (size_t)(ws_j * 32 + li) * 64 + 32 + lg8;
  // V A-frag base: row c = c0 + wv*32 + csub*16 + li, k = j = t*64 + jc*32 + lg*8
  const __hip_bfloat16* vR =
      vbf + ((size_t)b * C_ + c0 + wv * 32 + li) * VP_ + lg8;

  // Prologue reg loads: K(0) transient; K(1)->kO; V(0)->vE set; V(1)->vO set.
  bf8 k00 = *(const bf8*)kp;
  bf8 k01 = *(const bf8*)(kp + 16 * 64);
  bf8 kO0 = *(const bf8*)(kp + 64 * 64);
  bf8 kO1 = *(const bf8*)(kp + 64 * 64 + 16 * 64);
  bf8 kE0, kE1;
  bf8 vEA = *(const bf8*)vR;
  bf8 vEB = *(const bf8*)(vR + 32);
  bf8 vEC = *(const bf8*)(vR + 16 * VP_);
  bf8 vED = *(const bf8*)(vR + 16 * VP_ + 32);
  bf8 vOA = *(const bf8*)(vR + 64);
  bf8 vOB = *(const bf8*)(vR + 64 + 32);
  bf8 vOC = *(const bf8*)(vR + 16 * VP_ + 64);
  bf8 vOD = *(const bf8*)(vR + 16 * VP_ + 64 + 32);

  f4 acc[2][4] = {};
  float lp0 = 0.f, lp1 = 0.f;

  // Prologue S(0): exp2, pack, publish P(0) -> pS[0]
  {
    f4 s00 = {}, s01 = {}, s10 = {}, s11 = {};
    s00 = MFMA16(k00, qf0, s00);
    s01 = MFMA16(k00, qf1, s01);
    s10 = MFMA16(k01, qf0, s10);
    s11 = MFMA16(k01, qf1, s11);
#pragma unroll
    for (int m = 0; m < 4; ++m) {
      s00[m] = __builtin_amdgcn_exp2f(s00[m]);
      s01[m] = __builtin_amdgcn_exp2f(s01[m]);
      s10[m] = __builtin_amdgcn_exp2f(s10[m]);
      s11[m] = __builtin_amdgcn_exp2f(s11[m]);
    }
#pragma unroll
    for (int m = 0; m < 4; ++m) {
      lp0 += s00[m] + s10[m];
      lp1 += s01[m] + s11[m];
    }
    bf4 t0, t1, t2, t3;
#pragma unroll
    for (int m = 0; m < 4; ++m) {
      t0[m] = (__bf16)s00[m]; t1[m] = (__bf16)s01[m];
      t2[m] = (__bf16)s10[m]; t3[m] = (__bf16)s11[m];
    }
    *(bf4*)&pS[0][ws_i * 32 +  0 + li][ws_j * 32 +  0 + lg4] = t0;
    *(bf4*)&pS[0][ws_i * 32 + 16 + li][ws_j * 32 +  0 + lg4] = t1;
    *(bf4*)&pS[0][ws_i * 32 +  0 + li][ws_j * 32 + 16 + lg4] = t2;
    *(bf4*)&pS[0][ws_i * 32 + 16 + li][ws_j * 32 + 16 + lg4] = t3;
    asm volatile("s_waitcnt lgkmcnt(0)" ::: "memory");
    __builtin_amdgcn_sched_barrier(0);
    __builtin_amdgcn_s_barrier();
    __builtin_amdgcn_sched_barrier(0);
  }

  for (int tt = 0; tt < NT_; tt += 2) {
    ATTN_BODY(tt,     0, kO0, kO1, kE0, kE1, vEA, vEB, vEC, vED)
    ATTN_BODY(tt + 1, 1, kE0, kE1, kO0, kO1, vOA, vOB, vOC, vOD)
  }
#undef ATTN_BODY

  // Denominator: reduce over lg groups (same li), then cross-ws_j via LDS.
  lp0 += __shfl_xor(lp0, 16); lp0 += __shfl_xor(lp0, 32);
  lp1 += __shfl_xor(lp1, 16); lp1 += __shfl_xor(lp1, 32);
  if (lane < 16)      lSp[ws_j][ws_i * 32 + lane] = lp0;
  else if (lane < 32) lSp[ws_j][ws_i * 32 + 16 + (lane & 15)] = lp1;
  __syncthreads();
  float linv0 = 1.0f / (lSp[0][ 0 + li] + lSp[1][ 0 + li]);
  float linv1 = 1.0f / (lSp[0][16 + li] + lSp[1][16 + li]);
  float linv2 = 1.0f / (lSp[0][32 + li] + lSp[1][32 + li]);
  float linv3 = 1.0f / (lSp[0][48 + li] + lSp[1][48 + li]);

  const float* xr = x + (size_t)b * C_ * N_;
  float* op = out + (size_t)b * C_ * N_;
#pragma unroll
  for (int cs = 0; cs < 2; ++cs)
#pragma unroll
    for (int m = 0; m < 4; ++m) {
      int c = c0 + wv * 32 + cs * 16 + lg4 + m;
      size_t base = (size_t)c * N_ + i0;
      op[base +  0 + li] = acc[cs][0][m] * linv0 + xr[base +  0 + li];
      op[base + 16 + li] = acc[cs][1][m] * linv1 + xr[base + 16 + li];
      op[base + 32 + li] = acc[cs][2][m] * linv2 + xr[base + 32 + li];
      op[base + 48 + li] = acc[cs][3][m] * linv3 + xr[base + 48 + li];
    }
}

extern "C" void kernel_launch(void* const* d_in, const int* in_sizes, int n_in,
                              void* d_out, int out_size, void* d_ws, size_t ws_size,
                              hipStream_t stream) {
  const float* x  = (const float*)d_in[0];
  const float* wq = (const float*)d_in[1];
  const float* bq = (const float*)d_in[2];
  const float* wk = (const float*)d_in[3];
  const float* bk = (const float*)d_in[4];
  const float* wv = (const float*)d_in[5];
  const float* bv = (const float*)d_in[6];
  float* out = (float*)d_out;

  char* ws = (char*)d_ws;
  __hip_bfloat16* qkb = (__hip_bfloat16*)ws;                        // 2 MiB [b][n][64]
  __hip_bfloat16* vbf = (__hip_bfloat16*)(ws + (2u << 20));         // 8.06 MiB [b][c][VP_]
  __hip_bfloat16* wpk = (__hip_bfloat16*)(ws + 10551296u);          // 160 KiB [320][256]
  float*          bpk = (float*)(ws + 10551296u + 163840u);

  pack_kernel<<<dim3(320), 256, 0, stream>>>(wq, wk, wv, bq, bk, bv, wpk, bpk);
  proj_kernel<<<dim3(N_ / 32, B_), 256, 0, stream>>>(x, wpk, bpk, vbf, qkb);
  fused_attn<<<dim3(512), 256, 0, stream>>>(qkb, vbf, x, out);
}